// Round 9
// baseline (1364.417 us; speedup 1.0000x reference)
//
#include <hip/hip_runtime.h>

typedef __attribute__((ext_vector_type(4))) int i32x4;
typedef unsigned short u16;
typedef unsigned char u8;
typedef unsigned int u32;
typedef unsigned long long u64;

static constexpr int NROW = 16384;   // b*h*w
static constexpr int NCODE = 8192;
static constexpr int ZN = 4194304;   // b*c*h*w
static constexpr int CAP = 48;
static constexpr int MARGIN_I = 4200;   // 2.5e-4 * 2^24

// workspace layout (bytes) — 8 MB
static constexpr size_t OFF_ZB8  = 0;         // i8 granules z  4 MB
static constexpr size_t OFF_EB8  = 4194304;   // i8 granules e  2 MB
static constexpr size_t OFF_CNT  = 6291456;   // int [NROW]
static constexpr size_t OFF_CAND = 6356992;   // u16 [NROW][CAP]
static constexpr size_t OFF_LOSS = 7929856;   // float
static constexpr size_t OFF_CTR  = 7929860;   // int

__device__ __forceinline__ u64 shfl_xor_u64(u64 x, int m) {
  int lo = (int)(x & 0xffffffffull), hi = (int)(x >> 32);
  lo = __shfl_xor(lo, m);
  hi = __shfl_xor(hi, m);
  return ((u64)(u32)hi << 32) | (u32)lo;
}
__device__ __forceinline__ char q8(float v, float s) {
  int x = __float2int_rn(v * s);
  x = x < -128 ? -128 : (x > 127 ? 127 : x);
  return (char)x;
}

// ---- numpy fp32 replica (verified rounds 4-7; no FMA contraction) ----
#pragma clang fp contract(off)
__device__ float np_dist(const float* zr, const float* __restrict__ er, float A) {
  const float4* e4 = (const float4*)er;
  float s0 = 0.f, s1 = 0.f, s2 = 0.f, s3 = 0.f;
#pragma unroll 4
  for (int i16 = 0; i16 < 16; ++i16) {
    float4 ea = e4[i16 * 4 + 0], eb = e4[i16 * 4 + 1];
    float4 ec = e4[i16 * 4 + 2], ed = e4[i16 * 4 + 3];
    const float* zz = zr + i16 * 16;
    s0 = __fadd_rn(__fmul_rn(zz[0], ea.x),
         __fadd_rn(__fmul_rn(zz[4], eb.x),
         __fadd_rn(__fmul_rn(zz[8], ec.x),
         __fadd_rn(__fmul_rn(zz[12], ed.x), s0))));
    s1 = __fadd_rn(__fmul_rn(zz[1], ea.y),
         __fadd_rn(__fmul_rn(zz[5], eb.y),
         __fadd_rn(__fmul_rn(zz[9], ec.y),
         __fadd_rn(__fmul_rn(zz[13], ed.y), s1))));
    s2 = __fadd_rn(__fmul_rn(zz[2], ea.z),
         __fadd_rn(__fmul_rn(zz[6], eb.z),
         __fadd_rn(__fmul_rn(zz[10], ec.z),
         __fadd_rn(__fmul_rn(zz[14], ed.z), s2))));
    s3 = __fadd_rn(__fmul_rn(zz[3], ea.w),
         __fadd_rn(__fmul_rn(zz[7], eb.w),
         __fadd_rn(__fmul_rn(zz[11], ec.w),
         __fadd_rn(__fmul_rn(zz[15], ed.w), s3))));
  }
  float C = __fadd_rn(__fadd_rn(s0, s1), __fadd_rn(s2, s3));
  return __fadd_rn(A, -(2.0f * C));
}

// A = np pairwise-sum replica of ||z||^2 (verified rounds 4-7).
// Wave-collective: lanes 0..15 compute partials into red[16]; all lanes fold.
__device__ float np_rowA(const float* zrow, int lane, volatile float* red) {
  if (lane < 16) {
    const int half = lane >> 3, jj = lane & 7;
    const float* p = zrow + half * 128 + jj;
    float acc = __fmul_rn(p[0], p[0]);
    for (int i = 8; i < 128; i += 8) acc = __fadd_rn(acc, __fmul_rn(p[i], p[i]));
    red[lane] = acc;
  }
  float h0 = __fadd_rn(__fadd_rn(__fadd_rn(red[0], red[1]), __fadd_rn(red[2], red[3])),
                       __fadd_rn(__fadd_rn(red[4], red[5]), __fadd_rn(red[6], red[7])));
  float h1 = __fadd_rn(__fadd_rn(__fadd_rn(red[8], red[9]), __fadd_rn(red[10], red[11])),
                       __fadd_rn(__fadd_rn(red[12], red[13]), __fadd_rn(red[14], red[15])));
  return __fadd_rn(h0, h1);
}
#pragma clang fp contract(fast)

// ---- kernel 1: prep — z,e -> i8 lane-ordered granules; zero cnt/loss/ctr ----
// granule(tile16, kb, lane) 16B at tile*4096 + (kb*64+lane)*16;
// content = X[idx = tile*16 + (lane&15)][k = kb*64 + (lane>>4)*16 + j], j=0..15
__global__ __launch_bounds__(256) void prep_kernel(const float* __restrict__ z,
                                                   const float* __restrict__ e,
                                                   char* __restrict__ zb8,
                                                   char* __restrict__ eb8,
                                                   int* __restrict__ g_cnt,
                                                   float* __restrict__ loss_ws,
                                                   int* __restrict__ ctr) {
  const int blk = blockIdx.x;
  if (blk < 512) {
    __shared__ float t[256][33];
    const int b = blk >> 5, h = blk & 31;
    const int w = threadIdx.x & 31, cc = threadIdx.x >> 5;
    const float* src = z + (size_t)b * 262144 + h * 32 + w;
#pragma unroll
    for (int c0 = 0; c0 < 256; c0 += 8) t[c0 + cc][w] = src[(size_t)(c0 + cc) * 1024];
    if (threadIdx.x < 32) g_cnt[blk * 32 + threadIdx.x] = 0;
    if (blk == 0 && threadIdx.x == 0) { *loss_ws = 0.f; *ctr = 0; }
    __syncthreads();
#pragma unroll
    for (int gi = 0; gi < 2; ++gi) {
      const int g = gi * 256 + threadIdx.x;       // 512 granules/block
      const int kb = g >> 7, l4 = (g >> 5) & 3, w2 = g & 31;
      const int c0 = kb * 64 + l4 * 16;
      union { char c[16]; i32x4 v; } u;
#pragma unroll
      for (int j = 0; j < 16; ++j) u.c[j] = q8(t[c0 + j][w2], 16.0f);
      const int tile = blk * 2 + (w2 >> 4);
      *(i32x4*)(zb8 + (size_t)tile * 4096 + (size_t)(kb * 64 + l4 * 16 + (w2 & 15)) * 16) = u.v;
    }
  } else {
    const int G = (blk - 512) * 256 + threadIdx.x;   // granule id, 0..131071
    const int tile = G >> 8, r = G & 255;
    const int kb = r >> 6, lane = r & 63;
    const int l4 = lane >> 4, l15 = lane & 15;
    const float* s = e + (size_t)(tile * 16 + l15) * 256 + kb * 64 + l4 * 16;
    union { char c[16]; i32x4 v; } u;
#pragma unroll
    for (int j = 0; j < 16; ++j) u.c[j] = q8(s[j], 1048576.0f);
    *(i32x4*)(eb8 + (size_t)G * 16) = u.v;
  }
}

// ---- kernel 2: streaming i8 MFMA scores, no LDS staging, no K-loop barriers ----
// grid 512 = 256 row-groups x 2 code-halves; 512 thr = 8 waves, each 64 rows x 16 codes.
__global__ __launch_bounds__(512, 4) void scores_kernel(const char* __restrict__ zb8,
                                                        const char* __restrict__ eb8,
                                                        int* __restrict__ g_cnt,
                                                        u16* __restrict__ g_cand) {
  __shared__ int s_rm[64];
  const int tid = threadIdx.x;
  const int wave = tid >> 6, lane = tid & 63;
  const int l15 = lane & 15, l4 = lane >> 4;
  const int row0 = (int)(blockIdx.x >> 1) * 64;
  const int code0 = (int)(blockIdx.x & 1) * 4096;
  if (tid < 64) s_rm[tid] = INT_MIN;

  // persistent A fragments: 4 row-tiles x 4 k-blocks (coalesced 1KB loads)
  i32x4 a[4][4];
#pragma unroll
  for (int rt = 0; rt < 4; ++rt) {
    const i32x4* ab = (const i32x4*)(zb8 + (size_t)((row0 >> 4) + rt) * 4096);
#pragma unroll
    for (int kb = 0; kb < 4; ++kb) a[rt][kb] = ab[kb * 64 + lane];
  }
  __syncthreads();   // s_rm init visible

  const i32x4* ebase = (const i32x4*)eb8;
  int lmax[4][4];

#define COMPUTE(CH, ACC)                                                          \
  i32x4 ACC[4] = {{0,0,0,0},{0,0,0,0},{0,0,0,0},{0,0,0,0}};                       \
  {                                                                               \
    const i32x4* bt = ebase + (size_t)((code0 >> 4) + (CH) * 8 + wave) * 256;     \
    i32x4 bf0 = bt[lane], bf1 = bt[64 + lane], bf2 = bt[128 + lane], bf3 = bt[192 + lane]; \
    _Pragma("unroll")                                                             \
    for (int rt = 0; rt < 4; ++rt) {                                              \
      ACC[rt] = __builtin_amdgcn_mfma_i32_16x16x64_i8(a[rt][0], bf0, ACC[rt], 0, 0, 0); \
      ACC[rt] = __builtin_amdgcn_mfma_i32_16x16x64_i8(a[rt][1], bf1, ACC[rt], 0, 0, 0); \
      ACC[rt] = __builtin_amdgcn_mfma_i32_16x16x64_i8(a[rt][2], bf2, ACC[rt], 0, 0, 0); \
      ACC[rt] = __builtin_amdgcn_mfma_i32_16x16x64_i8(a[rt][3], bf3, ACC[rt], 0, 0, 0); \
    }                                                                             \
  }

#define SYNC_THR()                                                               \
  {                                                                              \
    _Pragma("unroll")                                                            \
    for (int rt = 0; rt < 4; ++rt)                                               \
      _Pragma("unroll")                                                          \
      for (int r = 0; r < 4; ++r) {                                              \
        int m = lmax[rt][r];                                                     \
        _Pragma("unroll")                                                        \
        for (int s = 1; s < 16; s <<= 1) m = max(m, __shfl_xor(m, s));           \
        if (l15 == 0) atomicMax(&s_rm[rt * 16 + l4 * 4 + r], m);                 \
      }                                                                          \
    __syncthreads();                                                             \
    _Pragma("unroll")                                                            \
    for (int rt = 0; rt < 4; ++rt)                                               \
      _Pragma("unroll")                                                          \
      for (int r = 0; r < 4; ++r)                                                \
        lmax[rt][r] = max(lmax[rt][r], s_rm[rt * 16 + l4 * 4 + r]);              \
  }

  {  // seed: chunk 0, maxes only
    COMPUTE(0, acc);
#pragma unroll
    for (int rt = 0; rt < 4; ++rt)
#pragma unroll
      for (int r = 0; r < 4; ++r) lmax[rt][r] = acc[rt][r];
  }
  SYNC_THR();

  for (int ch = 0; ch < 32; ++ch) {
    COMPUTE(ch, acc);
#pragma unroll
    for (int rt = 0; rt < 4; ++rt)
#pragma unroll
      for (int r = 0; r < 4; ++r) {
        const int v = acc[rt][r];
        if (v > lmax[rt][r] - MARGIN_I) {      // superset of final-threshold set
          const int rowg = row0 + rt * 16 + l4 * 4 + r;
          int p = atomicAdd(&g_cnt[rowg], 1);
          if (p < CAP)
            g_cand[(size_t)rowg * CAP + p] = (u16)(code0 + ch * 128 + wave * 16 + l15);
        }
        lmax[rt][r] = max(lmax[rt][r], v);
      }
    if ((ch & 3) == 3 && ch != 31) SYNC_THR();
  }
#undef COMPUTE
#undef SYNC_THR
}

// ---- kernel 3: pair-compacted numpy-replica rescore + z_st gather + loss ----
__global__ __launch_bounds__(256) void rescore_fin_kernel(const float* __restrict__ z,
                                                          const float* __restrict__ emb,
                                                          const int* __restrict__ g_cnt,
                                                          const u16* __restrict__ g_cand,
                                                          float* __restrict__ loss_ws,
                                                          int* __restrict__ ctr,
                                                          float* __restrict__ z_st,
                                                          float* __restrict__ out_loss,
                                                          float* __restrict__ out_idx) {
  __shared__ float zrows[32][257];
  __shared__ float red_s[4][16];
  __shared__ float A_s[32], D_s[32];
  __shared__ u64 best_s[32];
  __shared__ int widx_s[32], cnts[32], starts[33], ovf_list[32];
  __shared__ int nP, nOvf;
  __shared__ u8 prow[32 * CAP];
  __shared__ u16 pidx[32 * CAP];
  const int bh = blockIdx.x;
  const int b = bh >> 5, h = bh & 31;
  const int n0 = bh * 32;
  const int wave = threadIdx.x >> 6, lane = threadIdx.x & 63;
  {
    const float* src = z + (size_t)b * 262144 + h * 32;
    const int w = threadIdx.x & 31, c8 = threadIdx.x >> 5;
#pragma unroll
    for (int c0 = 0; c0 < 256; c0 += 8) {
      int c = c0 + c8;
      zrows[w][c] = src[(size_t)c * 1024 + w];
    }
  }
  if (threadIdx.x < 32) best_s[threadIdx.x] = ~0ull;
  __syncthreads();

  // A = np pairwise-sum replica, wave handles 8 rows (file-scope pragma helper)
  for (int j = 0; j < 8; ++j) {
    const int r = wave * 8 + j;
    float A = np_rowA(zrows[r], lane, red_s[wave]);
    if (lane == 0) A_s[r] = A;
  }
  if (threadIdx.x < 32) {
    const int c = g_cnt[n0 + threadIdx.x];
    cnts[threadIdx.x] = c > CAP ? 0 : c;     // overflow rows go to fallback
  }
  __syncthreads();
  if (threadIdx.x == 0) {
    int acc = 0, no = 0;
    for (int r = 0; r < 32; ++r) {
      starts[r] = acc;
      acc += cnts[r];
      if (cnts[r] == 0) ovf_list[no++] = r;  // cnt>CAP (cnt==0 impossible otherwise)
    }
    starts[32] = acc; nP = acc; nOvf = no;
  }
  __syncthreads();
  if (threadIdx.x < 32) {
    const int r = threadIdx.x, s0 = starts[r], c = cnts[r];
    for (int j = 0; j < c; ++j) {
      prow[s0 + j] = (u8)r;
      pidx[s0 + j] = g_cand[(size_t)(n0 + r) * CAP + j];
    }
  }
  __syncthreads();

  const int P = nP;
  for (int p = threadIdx.x; p < P; p += 256) {
    const int r = prow[p], idx = (int)pidx[p];
    float D = np_dist(zrows[r], emb + (size_t)idx * 256, A_s[r]);
    u64 key = ((u64)__float_as_uint(D) << 16) | (u32)idx;
    atomicMin(&best_s[r], key);
  }
  __syncthreads();

  // overflow fallback (P ~ 0): full replica scan, one wave per flagged row
  for (int i = wave; i < nOvf; i += 4) {
    const int r = ovf_list[i];
    u64 bestkey = ~0ull;
    for (int idx = lane; idx < NCODE; idx += 64) {
      float D = np_dist(zrows[r], emb + (size_t)idx * 256, A_s[r]);
      u64 k = ((u64)__float_as_uint(D) << 16) | (u32)idx;
      if (k < bestkey) bestkey = k;
    }
#pragma unroll
    for (int m = 32; m >= 1; m >>= 1) {
      u64 o = shfl_xor_u64(bestkey, m);
      if (o < bestkey) bestkey = o;
    }
    if (lane == 0) atomicMin(&best_s[r], bestkey);
  }
  __syncthreads();

  if (threadIdx.x < 32) {
    const int r = threadIdx.x;
    const u64 k = best_s[r];
    const int bidx = (int)(k & 0xFFFF);
    widx_s[r] = bidx;
    out_idx[n0 + r] = (float)bidx;
    D_s[r] = __uint_as_float((u32)(k >> 16));
  }
  __syncthreads();
  if (threadIdx.x == 0) {
    float s = 0.f;
    for (int r = 0; r < 32; ++r) s += D_s[r];
    atomicAdd(loss_ws, s);
    __threadfence();
    int t = atomicAdd(ctr, 1);
    if (t == 511)
      *out_loss = atomicAdd(loss_ws, 0.0f) * (1.25f / 4194304.0f);
  }

  for (int wi = 0; wi < 32; ++wi)
    zrows[wi][threadIdx.x] = emb[(size_t)widx_s[wi] * 256 + threadIdx.x];
  __syncthreads();
  const int w = threadIdx.x & 31, c0 = threadIdx.x >> 5;
  float* dst = z_st + (size_t)b * 262144 + h * 32 + w;
#pragma unroll
  for (int cj = 0; cj < 32; ++cj) {
    int c = c0 + cj * 8;
    dst[(size_t)c * 1024] = zrows[w][c];
  }
}

extern "C" void kernel_launch(void* const* d_in, const int* in_sizes, int n_in,
                              void* d_out, int out_size, void* d_ws, size_t ws_size,
                              hipStream_t stream) {
  const float* z = (const float*)d_in[0];     // fp32 [16,256,32,32]
  const float* emb = (const float*)d_in[1];   // fp32 [8192,256]
  char* ws = (char*)d_ws;
  char* zb8 = ws + OFF_ZB8;
  char* eb8 = ws + OFF_EB8;
  int* g_cnt = (int*)(ws + OFF_CNT);
  u16* g_cand = (u16*)(ws + OFF_CAND);
  float* loss_ws = (float*)(ws + OFF_LOSS);
  int* ctr = (int*)(ws + OFF_CTR);
  float* out = (float*)d_out;
  float* out_loss = out + ZN;       // output 1
  float* out_idx = out + ZN + 1;    // output 2

  prep_kernel<<<1024, 256, 0, stream>>>(z, emb, zb8, eb8, g_cnt, loss_ws, ctr);
  scores_kernel<<<512, 512, 0, stream>>>(zb8, eb8, g_cnt, g_cand);
  rescore_fin_kernel<<<512, 256, 0, stream>>>(z, emb, g_cnt, g_cand, loss_ws, ctr,
                                              out, out_loss, out_idx);
}

// Round 10
// 290.541 us; speedup vs baseline: 4.6961x; 4.6961x over previous
//
#include <hip/hip_runtime.h>

typedef __attribute__((ext_vector_type(4))) int i32x4;
typedef unsigned short u16;
typedef unsigned char u8;
typedef unsigned int u32;
typedef unsigned long long u64;

static constexpr int NROW = 16384;   // b*h*w
static constexpr int NCODE = 8192;
static constexpr int ZN = 4194304;   // b*c*h*w
static constexpr int CAP = 128;
static constexpr int MARGIN_I = 4200;   // 2.5e-4 * 2^24

// workspace layout (bytes) — 10.6 MB
static constexpr size_t OFF_ZB8  = 0;          // i8 granules z  4 MB
static constexpr size_t OFF_EB8  = 4194304;    // i8 granules e  2 MB
static constexpr size_t OFF_CNT  = 6291456;    // int [NROW]
static constexpr size_t OFF_CAND = 6356992;    // u16 [NROW][CAP]  4 MB
static constexpr size_t OFF_LOSS = 10551296;   // float
static constexpr size_t OFF_CTR  = 10551300;   // int

__device__ __forceinline__ u64 shfl_xor_u64(u64 x, int m) {
  int lo = (int)(x & 0xffffffffull), hi = (int)(x >> 32);
  lo = __shfl_xor(lo, m);
  hi = __shfl_xor(hi, m);
  return ((u64)(u32)hi << 32) | (u32)lo;
}
__device__ __forceinline__ char q8(float v, float s) {
  int x = __float2int_rn(v * s);
  x = x < -128 ? -128 : (x > 127 ? 127 : x);
  return (char)x;
}

// ---- numpy fp32 replica (verified rounds 4-9; no FMA contraction) ----
#pragma clang fp contract(off)
__device__ float np_dist(const float* zr, const float* __restrict__ er, float A) {
  const float4* e4 = (const float4*)er;
  float s0 = 0.f, s1 = 0.f, s2 = 0.f, s3 = 0.f;
#pragma unroll 4
  for (int i16 = 0; i16 < 16; ++i16) {
    float4 ea = e4[i16 * 4 + 0], eb = e4[i16 * 4 + 1];
    float4 ec = e4[i16 * 4 + 2], ed = e4[i16 * 4 + 3];
    const float* zz = zr + i16 * 16;
    s0 = __fadd_rn(__fmul_rn(zz[0], ea.x),
         __fadd_rn(__fmul_rn(zz[4], eb.x),
         __fadd_rn(__fmul_rn(zz[8], ec.x),
         __fadd_rn(__fmul_rn(zz[12], ed.x), s0))));
    s1 = __fadd_rn(__fmul_rn(zz[1], ea.y),
         __fadd_rn(__fmul_rn(zz[5], eb.y),
         __fadd_rn(__fmul_rn(zz[9], ec.y),
         __fadd_rn(__fmul_rn(zz[13], ed.y), s1))));
    s2 = __fadd_rn(__fmul_rn(zz[2], ea.z),
         __fadd_rn(__fmul_rn(zz[6], eb.z),
         __fadd_rn(__fmul_rn(zz[10], ec.z),
         __fadd_rn(__fmul_rn(zz[14], ed.z), s2))));
    s3 = __fadd_rn(__fmul_rn(zz[3], ea.w),
         __fadd_rn(__fmul_rn(zz[7], eb.w),
         __fadd_rn(__fmul_rn(zz[11], ec.w),
         __fadd_rn(__fmul_rn(zz[15], ed.w), s3))));
  }
  float C = __fadd_rn(__fadd_rn(s0, s1), __fadd_rn(s2, s3));
  return __fadd_rn(A, -(2.0f * C));
}

// A = np pairwise-sum replica of ||z||^2 (verified rounds 4-9).
__device__ float np_rowA(const float* zrow, int lane, volatile float* red) {
  if (lane < 16) {
    const int half = lane >> 3, jj = lane & 7;
    const float* p = zrow + half * 128 + jj;
    float acc = __fmul_rn(p[0], p[0]);
    for (int i = 8; i < 128; i += 8) acc = __fadd_rn(acc, __fmul_rn(p[i], p[i]));
    red[lane] = acc;
  }
  float h0 = __fadd_rn(__fadd_rn(__fadd_rn(red[0], red[1]), __fadd_rn(red[2], red[3])),
                       __fadd_rn(__fadd_rn(red[4], red[5]), __fadd_rn(red[6], red[7])));
  float h1 = __fadd_rn(__fadd_rn(__fadd_rn(red[8], red[9]), __fadd_rn(red[10], red[11])),
                       __fadd_rn(__fadd_rn(red[12], red[13]), __fadd_rn(red[14], red[15])));
  return __fadd_rn(h0, h1);
}
#pragma clang fp contract(fast)

// ---- kernel 1: prep — z,e -> i8 lane-ordered granules; zero cnt/loss/ctr ----
__global__ __launch_bounds__(256) void prep_kernel(const float* __restrict__ z,
                                                   const float* __restrict__ e,
                                                   char* __restrict__ zb8,
                                                   char* __restrict__ eb8,
                                                   int* __restrict__ g_cnt,
                                                   float* __restrict__ loss_ws,
                                                   int* __restrict__ ctr) {
  const int blk = blockIdx.x;
  if (blk < 512) {
    __shared__ float t[256][33];
    const int b = blk >> 5, h = blk & 31;
    const int w = threadIdx.x & 31, cc = threadIdx.x >> 5;
    const float* src = z + (size_t)b * 262144 + h * 32 + w;
#pragma unroll
    for (int c0 = 0; c0 < 256; c0 += 8) t[c0 + cc][w] = src[(size_t)(c0 + cc) * 1024];
    if (threadIdx.x < 32) g_cnt[blk * 32 + threadIdx.x] = 0;
    if (blk == 0 && threadIdx.x == 0) { *loss_ws = 0.f; *ctr = 0; }
    __syncthreads();
#pragma unroll
    for (int gi = 0; gi < 2; ++gi) {
      const int g = gi * 256 + threadIdx.x;
      const int kb = g >> 7, l4 = (g >> 5) & 3, w2 = g & 31;
      const int c0 = kb * 64 + l4 * 16;
      union { char c[16]; i32x4 v; } u;
#pragma unroll
      for (int j = 0; j < 16; ++j) u.c[j] = q8(t[c0 + j][w2], 16.0f);
      const int tile = blk * 2 + (w2 >> 4);
      *(i32x4*)(zb8 + (size_t)tile * 4096 + (size_t)(kb * 64 + l4 * 16 + (w2 & 15)) * 16) = u.v;
    }
  } else {
    const int G = (blk - 512) * 256 + threadIdx.x;
    const int tile = G >> 8, r = G & 255;
    const int kb = r >> 6, lane = r & 63;
    const int l4 = lane >> 4, l15 = lane & 15;
    const float* s = e + (size_t)(tile * 16 + l15) * 256 + kb * 64 + l4 * 16;
    union { char c[16]; i32x4 v; } u;
#pragma unroll
    for (int j = 0; j < 16; ++j) u.c[j] = q8(s[j], 1048576.0f);
    *(i32x4*)(eb8 + (size_t)G * 16) = u.v;
  }
}

// ---- kernel 2: streaming i8 MFMA scores; 4-chunk seed, sync every 2 chunks ----
__global__ __launch_bounds__(512, 4) void scores_kernel(const char* __restrict__ zb8,
                                                        const char* __restrict__ eb8,
                                                        int* __restrict__ g_cnt,
                                                        u16* __restrict__ g_cand) {
  __shared__ int s_rm[64];
  const int tid = threadIdx.x;
  const int wave = tid >> 6, lane = tid & 63;
  const int l15 = lane & 15, l4 = lane >> 4;
  const int row0 = (int)(blockIdx.x >> 1) * 64;
  const int code0 = (int)(blockIdx.x & 1) * 4096;
  if (tid < 64) s_rm[tid] = INT_MIN;

  i32x4 a[4][4];
#pragma unroll
  for (int rt = 0; rt < 4; ++rt) {
    const i32x4* ab = (const i32x4*)(zb8 + (size_t)((row0 >> 4) + rt) * 4096);
#pragma unroll
    for (int kb = 0; kb < 4; ++kb) a[rt][kb] = ab[kb * 64 + lane];
  }
  __syncthreads();   // s_rm init visible

  const i32x4* ebase = (const i32x4*)eb8;
  int lmax[4][4];

#define COMPUTE(CH, ACC)                                                          \
  i32x4 ACC[4] = {{0,0,0,0},{0,0,0,0},{0,0,0,0},{0,0,0,0}};                       \
  {                                                                               \
    const i32x4* bt = ebase + (size_t)((code0 >> 4) + (CH) * 8 + wave) * 256;     \
    i32x4 bf0 = bt[lane], bf1 = bt[64 + lane], bf2 = bt[128 + lane], bf3 = bt[192 + lane]; \
    _Pragma("unroll")                                                             \
    for (int rt = 0; rt < 4; ++rt) {                                              \
      ACC[rt] = __builtin_amdgcn_mfma_i32_16x16x64_i8(a[rt][0], bf0, ACC[rt], 0, 0, 0); \
      ACC[rt] = __builtin_amdgcn_mfma_i32_16x16x64_i8(a[rt][1], bf1, ACC[rt], 0, 0, 0); \
      ACC[rt] = __builtin_amdgcn_mfma_i32_16x16x64_i8(a[rt][2], bf2, ACC[rt], 0, 0, 0); \
      ACC[rt] = __builtin_amdgcn_mfma_i32_16x16x64_i8(a[rt][3], bf3, ACC[rt], 0, 0, 0); \
    }                                                                             \
  }

#define SYNC_THR()                                                               \
  {                                                                              \
    _Pragma("unroll")                                                            \
    for (int rt = 0; rt < 4; ++rt)                                               \
      _Pragma("unroll")                                                          \
      for (int r = 0; r < 4; ++r) {                                              \
        int m = lmax[rt][r];                                                     \
        _Pragma("unroll")                                                        \
        for (int s = 1; s < 16; s <<= 1) m = max(m, __shfl_xor(m, s));           \
        if (l15 == 0) atomicMax(&s_rm[rt * 16 + l4 * 4 + r], m);                 \
      }                                                                          \
    __syncthreads();                                                             \
    _Pragma("unroll")                                                            \
    for (int rt = 0; rt < 4; ++rt)                                               \
      _Pragma("unroll")                                                          \
      for (int r = 0; r < 4; ++r)                                                \
        lmax[rt][r] = max(lmax[rt][r], s_rm[rt * 16 + l4 * 4 + r]);              \
  }

  // seed: chunks 0..3 (512 codes), maxes only — no pushes against a cold threshold
  for (int ch = 0; ch < 4; ++ch) {
    COMPUTE(ch, acc);
    if (ch == 0) {
#pragma unroll
      for (int rt = 0; rt < 4; ++rt)
#pragma unroll
        for (int r = 0; r < 4; ++r) lmax[rt][r] = acc[rt][r];
    } else {
#pragma unroll
      for (int rt = 0; rt < 4; ++rt)
#pragma unroll
        for (int r = 0; r < 4; ++r) lmax[rt][r] = max(lmax[rt][r], acc[rt][r]);
    }
  }
  SYNC_THR();

  for (int ch = 0; ch < 32; ++ch) {
    COMPUTE(ch, acc);
#pragma unroll
    for (int rt = 0; rt < 4; ++rt)
#pragma unroll
      for (int r = 0; r < 4; ++r) {
        const int v = acc[rt][r];
        if (v > lmax[rt][r] - MARGIN_I) {      // superset of final-threshold set
          const int rowg = row0 + rt * 16 + l4 * 4 + r;
          int p = atomicAdd(&g_cnt[rowg], 1);
          if (p < CAP)
            g_cand[(size_t)rowg * CAP + p] = (u16)(code0 + ch * 128 + wave * 16 + l15);
        }
        lmax[rt][r] = max(lmax[rt][r], v);
      }
    if ((ch & 1) == 1 && ch != 31) SYNC_THR();
  }
#undef COMPUTE
#undef SYNC_THR
}

// ---- kernel 3: pair-compacted numpy-replica rescore + z_st gather + loss ----
__global__ __launch_bounds__(256) void rescore_fin_kernel(const float* __restrict__ z,
                                                          const float* __restrict__ emb,
                                                          const int* __restrict__ g_cnt,
                                                          const u16* __restrict__ g_cand,
                                                          float* __restrict__ loss_ws,
                                                          int* __restrict__ ctr,
                                                          float* __restrict__ z_st,
                                                          float* __restrict__ out_loss,
                                                          float* __restrict__ out_idx) {
  __shared__ float zrows[32][257];
  __shared__ float red_s[4][16];
  __shared__ float A_s[32], D_s[32];
  __shared__ u64 best_s[32];
  __shared__ int widx_s[32], cnts[32], starts[33], ovf_list[32];
  __shared__ int nP, nOvf;
  __shared__ u8 prow[32 * CAP];
  __shared__ u16 pidx[32 * CAP];
  const int bh = blockIdx.x;
  const int b = bh >> 5, h = bh & 31;
  const int n0 = bh * 32;
  const int wave = threadIdx.x >> 6, lane = threadIdx.x & 63;
  {
    const float* src = z + (size_t)b * 262144 + h * 32;
    const int w = threadIdx.x & 31, c8 = threadIdx.x >> 5;
#pragma unroll
    for (int c0 = 0; c0 < 256; c0 += 8) {
      int c = c0 + c8;
      zrows[w][c] = src[(size_t)c * 1024 + w];
    }
  }
  if (threadIdx.x < 32) best_s[threadIdx.x] = ~0ull;
  __syncthreads();

  for (int j = 0; j < 8; ++j) {
    const int r = wave * 8 + j;
    float A = np_rowA(zrows[r], lane, red_s[wave]);
    if (lane == 0) A_s[r] = A;
  }
  if (threadIdx.x < 32) {
    const int c = g_cnt[n0 + threadIdx.x];
    cnts[threadIdx.x] = c > CAP ? 0 : c;     // overflow rows -> block-wide fallback
  }
  __syncthreads();
  if (threadIdx.x == 0) {
    int acc = 0, no = 0;
    for (int r = 0; r < 32; ++r) {
      starts[r] = acc;
      acc += cnts[r];
      if (cnts[r] == 0) ovf_list[no++] = r;  // cnt>CAP (cnt>=1 otherwise guaranteed)
    }
    starts[32] = acc; nP = acc; nOvf = no;
  }
  __syncthreads();
  if (threadIdx.x < 32) {
    const int r = threadIdx.x, s0 = starts[r], c = cnts[r];
    for (int j = 0; j < c; ++j) {
      prow[s0 + j] = (u8)r;
      pidx[s0 + j] = g_cand[(size_t)(n0 + r) * CAP + j];
    }
  }
  __syncthreads();

  const int P = nP;
  for (int p = threadIdx.x; p < P; p += 256) {
    const int r = prow[p], idx = (int)pidx[p];
    float D = np_dist(zrows[r], emb + (size_t)idx * 256, A_s[r]);
    u64 key = ((u64)__float_as_uint(D) << 16) | (u32)idx;
    atomicMin(&best_s[r], key);
  }
  __syncthreads();

  // overflow fallback (P ~ 0): block-wide scan, 32 np_dists/thread per row
  for (int i = 0; i < nOvf; ++i) {
    const int r = ovf_list[i];
    for (int idx = threadIdx.x; idx < NCODE; idx += 256) {
      float D = np_dist(zrows[r], emb + (size_t)idx * 256, A_s[r]);
      u64 k = ((u64)__float_as_uint(D) << 16) | (u32)idx;
      atomicMin(&best_s[r], k);
    }
  }
  if (nOvf) __syncthreads();

  if (threadIdx.x < 32) {
    const int r = threadIdx.x;
    const u64 k = best_s[r];
    const int bidx = (int)(k & 0xFFFF);
    widx_s[r] = bidx;
    out_idx[n0 + r] = (float)bidx;
    D_s[r] = __uint_as_float((u32)(k >> 16));
  }
  __syncthreads();
  if (threadIdx.x == 0) {
    float s = 0.f;
    for (int r = 0; r < 32; ++r) s += D_s[r];
    atomicAdd(loss_ws, s);
    __threadfence();
    int t = atomicAdd(ctr, 1);
    if (t == 511)
      *out_loss = atomicAdd(loss_ws, 0.0f) * (1.25f / 4194304.0f);
  }

  for (int wi = 0; wi < 32; ++wi)
    zrows[wi][threadIdx.x] = emb[(size_t)widx_s[wi] * 256 + threadIdx.x];
  __syncthreads();
  const int w = threadIdx.x & 31, c0 = threadIdx.x >> 5;
  float* dst = z_st + (size_t)b * 262144 + h * 32 + w;
#pragma unroll
  for (int cj = 0; cj < 32; ++cj) {
    int c = c0 + cj * 8;
    dst[(size_t)c * 1024] = zrows[w][c];
  }
}

extern "C" void kernel_launch(void* const* d_in, const int* in_sizes, int n_in,
                              void* d_out, int out_size, void* d_ws, size_t ws_size,
                              hipStream_t stream) {
  const float* z = (const float*)d_in[0];     // fp32 [16,256,32,32]
  const float* emb = (const float*)d_in[1];   // fp32 [8192,256]
  char* ws = (char*)d_ws;
  char* zb8 = ws + OFF_ZB8;
  char* eb8 = ws + OFF_EB8;
  int* g_cnt = (int*)(ws + OFF_CNT);
  u16* g_cand = (u16*)(ws + OFF_CAND);
  float* loss_ws = (float*)(ws + OFF_LOSS);
  int* ctr = (int*)(ws + OFF_CTR);
  float* out = (float*)d_out;
  float* out_loss = out + ZN;       // output 1
  float* out_idx = out + ZN + 1;    // output 2

  prep_kernel<<<1024, 256, 0, stream>>>(z, emb, zb8, eb8, g_cnt, loss_ws, ctr);
  scores_kernel<<<512, 512, 0, stream>>>(zb8, eb8, g_cnt, g_cand);
  rescore_fin_kernel<<<512, 256, 0, stream>>>(z, emb, g_cnt, g_cand, loss_ws, ctr,
                                              out, out_loss, out_idx);
}